// Round 1
// baseline (488.119 us; speedup 1.0000x reference)
//
#include <hip/hip_runtime.h>
#include <hip/hip_bf16.h>
#include <cstdint>
#include <cstddef>

// CausalSelfAttention: B=4, T=2048, C=1024, H=16, hs=64 (fp32 in/out, bf16 MFMA compute)
//
// Pipeline: x->bf16 | W_attn,W_proj -> transposed bf16 | GEMM1 (qkv) |
//           flash attention (swapped-operand 16x16x32 MFMA) | GEMM2 (out)
//
// Workspace layout (needs 96 MiB):
//   [0,16M)   x_bf16        (8192 x 1024)
//   [16M,22M) W_attn^T bf16 (3072 x 1024)
//   [24M,26M) W_proj^T bf16 (1024 x 1024)
//   [32M,80M) qkv bf16      (8192 x 3072)
//   [80M,96M) y bf16        (8192 x 1024)

typedef unsigned short ushort_t;
typedef __attribute__((ext_vector_type(8))) short short8;
typedef __attribute__((ext_vector_type(4))) float f32x4;

#define AS1 __attribute__((address_space(1)))
#define AS3 __attribute__((address_space(3)))

__device__ __forceinline__ ushort_t f2bf(float f) {
  union { float f; unsigned u; } c; c.f = f;
  unsigned u = c.u;
  return (ushort_t)((u + 0x7FFFu + ((u >> 16) & 1u)) >> 16);  // RNE
}

// ---------------- fp32 -> bf16 elementwise (8 elems/thread) ----------------
__global__ __launch_bounds__(256) void k_f32_to_bf16(const float* __restrict__ in,
                                                     ushort_t* __restrict__ out) {
  const size_t i = ((size_t)blockIdx.x * 256 + threadIdx.x) * 8;
  f32x4 a = *(const f32x4*)(in + i);
  f32x4 b = *(const f32x4*)(in + i + 4);
  short8 o;
  o[0] = (short)f2bf(a[0]); o[1] = (short)f2bf(a[1]);
  o[2] = (short)f2bf(a[2]); o[3] = (short)f2bf(a[3]);
  o[4] = (short)f2bf(b[0]); o[5] = (short)f2bf(b[1]);
  o[6] = (short)f2bf(b[2]); o[7] = (short)f2bf(b[3]);
  *(short8*)(out + i) = o;
}

// ------------- fp32 (R x C) -> bf16 transposed (C x R), LDS-tiled ----------
__global__ __launch_bounds__(256) void k_transpose_bf16(const float* __restrict__ in,
                                                        ushort_t* __restrict__ out,
                                                        int R, int C) {
  __shared__ float tile[32][33];  // +1 pad: no bank conflicts
  const int tx = threadIdx.x & 31, ty = threadIdx.x >> 5;  // 32x8
  const int c0 = blockIdx.x * 32, r0 = blockIdx.y * 32;
#pragma unroll
  for (int i = 0; i < 32; i += 8)
    tile[ty + i][tx] = in[(size_t)(r0 + ty + i) * C + c0 + tx];
  __syncthreads();
#pragma unroll
  for (int i = 0; i < 32; i += 8)
    out[(size_t)(c0 + ty + i) * R + r0 + tx] = f2bf(tile[tx][ty + i]);
}

// ---------------- bf16 GEMM: C[M,N] = A[M,K] * Bt[N,K]^T -------------------
// 128x128 tile, BK=64, 4 waves (2x2), 16x16x32 MFMA, global_load_lds w=16.
template <bool OUT_BF16>
__global__ __launch_bounds__(256) void k_gemm_bt(const ushort_t* __restrict__ A,
                                                 const ushort_t* __restrict__ Bt,
                                                 void* __restrict__ Cout,
                                                 int N, int K) {
  __shared__ ushort_t As[128 * 64];
  __shared__ ushort_t Bs[128 * 64];
  const int tid = threadIdx.x;
  const int wave = tid >> 6, lane = tid & 63;
  const int c = lane & 15, g = lane >> 4;
  const int wm = wave >> 1, wn = wave & 1;
  const int bx = blockIdx.x, by = blockIdx.y;

  f32x4 acc[4][4];
#pragma unroll
  for (int m = 0; m < 4; m++)
#pragma unroll
    for (int n = 0; n < 4; n++) acc[m][n] = (f32x4){0.f, 0.f, 0.f, 0.f};

  for (int k0 = 0; k0 < K; k0 += 64) {
#pragma unroll
    for (int i = 0; i < 4; i++) {
      const int flat = i * 256 + tid;
      const ushort_t* srcA = A + (size_t)(by * 128 + (flat >> 3)) * K + k0 + (flat & 7) * 8;
      const ushort_t* srcB = Bt + (size_t)(bx * 128 + (flat >> 3)) * K + k0 + (flat & 7) * 8;
      const int ldsoff = (i * 256 + wave * 64) * 16;  // bytes; dest = base + lane*16
      __builtin_amdgcn_global_load_lds((const AS1 void*)srcA,
                                       (AS3 void*)((char*)As + ldsoff), 16, 0, 0);
      __builtin_amdgcn_global_load_lds((const AS1 void*)srcB,
                                       (AS3 void*)((char*)Bs + ldsoff), 16, 0, 0);
    }
    __syncthreads();
#pragma unroll
    for (int kk = 0; kk < 2; kk++) {
      short8 af[4], bfr[4];
#pragma unroll
      for (int m = 0; m < 4; m++)
        af[m] = *(const short8*)(As + (wm * 64 + m * 16 + c) * 64 + kk * 32 + g * 8);
#pragma unroll
      for (int n = 0; n < 4; n++)
        bfr[n] = *(const short8*)(Bs + (wn * 64 + n * 16 + c) * 64 + kk * 32 + g * 8);
#pragma unroll
      for (int m = 0; m < 4; m++)
#pragma unroll
        for (int n = 0; n < 4; n++)
          acc[m][n] = __builtin_amdgcn_mfma_f32_16x16x32_bf16(af[m], bfr[n], acc[m][n], 0, 0, 0);
    }
    __syncthreads();
  }

  // D layout: row=(lane>>4)*4+r, col=lane&15  [m89/m91]
#pragma unroll
  for (int m = 0; m < 4; m++)
#pragma unroll
    for (int n = 0; n < 4; n++) {
      const int col = bx * 128 + wn * 64 + n * 16 + c;
#pragma unroll
      for (int r = 0; r < 4; r++) {
        const int row = by * 128 + wm * 64 + m * 16 + g * 4 + r;
        if (OUT_BF16)
          ((ushort_t*)Cout)[(size_t)row * N + col] = f2bf(acc[m][n][r]);
        else
          ((float*)Cout)[(size_t)row * N + col] = acc[m][n][r];
      }
    }
}

// ---------------- flash attention, causal, hs=64 ----------------------------
// Grid (T/64, H, B), 4 waves/block, each wave owns 16 q-rows.
// S^T = K*Q^T (so q = lane&15 for softmax stats), y^T = V^T*P^T
// (so accumulator also has q = lane&15: rescale/normalize shuffle-free).
__global__ __launch_bounds__(256) void k_attn(const ushort_t* __restrict__ qkv,
                                              ushort_t* __restrict__ y) {
  const int T = 2048, C3 = 3072, Cc = 1024;
  const int tid = threadIdx.x;
  const int wave = tid >> 6, lane = tid & 63;
  const int c = lane & 15, g = lane >> 4;
  const int b = blockIdx.z, h = blockIdx.y;
  const int qbase = blockIdx.x * 64 + wave * 16;
  const size_t base = (size_t)b * T * C3 + h * 64;
  const ushort_t* Q = qkv + base;
  const ushort_t* Kp = qkv + base + 1024;
  const ushort_t* V = qkv + base + 2048;
  const float L2E = 1.44269504f;

  // Q^T B-fragment: lane holds Q[qbase+c][kk*32 + g*8 + r]
  short8 qf0, qf1;
  {
    const ushort_t* qp = Q + (size_t)(qbase + c) * C3 + g * 8;
    qf0 = *(const short8*)qp;
    qf1 = *(const short8*)(qp + 32);
  }

  f32x4 yacc[4];
#pragma unroll
  for (int dc = 0; dc < 4; dc++) yacc[dc] = (f32x4){0.f, 0.f, 0.f, 0.f};
  float m = -3.0e38f, ssum = 0.f;

  const int nk = qbase + 16;  // keys needed: 0..qbase+15
  for (int kb = 0; kb < nk; kb += 32) {
    // K A-fragments: lane holds K[kb + sub*16 + c][kk*32 + g*8 + r]
    const ushort_t* kp0 = Kp + (size_t)(kb + c) * C3 + g * 8;
    const ushort_t* kp1 = kp0 + (size_t)16 * C3;
    short8 kf00 = *(const short8*)kp0;
    short8 kf01 = *(const short8*)(kp0 + 32);
    short8 kf10 = *(const short8*)kp1;
    short8 kf11 = *(const short8*)(kp1 + 32);

    const f32x4 z = (f32x4){0.f, 0.f, 0.f, 0.f};
    f32x4 s0 = __builtin_amdgcn_mfma_f32_16x16x32_bf16(kf00, qf0, z, 0, 0, 0);
    s0 = __builtin_amdgcn_mfma_f32_16x16x32_bf16(kf01, qf1, s0, 0, 0, 0);
    f32x4 s1 = __builtin_amdgcn_mfma_f32_16x16x32_bf16(kf10, qf0, z, 0, 0, 0);
    s1 = __builtin_amdgcn_mfma_f32_16x16x32_bf16(kf11, qf1, s1, 0, 0, 0);

    // lane holds S[q=qbase+c][key = kb + sub*16 + g*4 + reg]
    float sv[8];
#pragma unroll
    for (int r = 0; r < 4; r++) { sv[r] = s0[r] * 0.125f; sv[4 + r] = s1[r] * 0.125f; }

    const int q = qbase + c;
    if (kb + 31 > qbase) {  // wave-uniform: diagonal tile needs causal mask
#pragma unroll
      for (int j = 0; j < 8; j++) {
        const int key = kb + ((j >> 2) << 4) + g * 4 + (j & 3);
        if (key > q) sv[j] = -3.0e38f;
      }
    }

    // row stats: q = lane&15, replicated over the 4 lane-groups
    float tm = sv[0];
#pragma unroll
    for (int j = 1; j < 8; j++) tm = fmaxf(tm, sv[j]);
    tm = fmaxf(tm, __shfl_xor(tm, 16));
    tm = fmaxf(tm, __shfl_xor(tm, 32));
    const float mnew = fmaxf(m, tm);

    float p[8], ts = 0.f;
#pragma unroll
    for (int j = 0; j < 8; j++) { p[j] = exp2f((sv[j] - mnew) * L2E); ts += p[j]; }
    ts += __shfl_xor(ts, 16);
    ts += __shfl_xor(ts, 32);
    const float alpha = exp2f((m - mnew) * L2E);
    ssum = ssum * alpha + ts;
    m = mnew;
#pragma unroll
    for (int dc = 0; dc < 4; dc++)
#pragma unroll
      for (int r = 0; r < 4; r++) yacc[dc][r] *= alpha;

    // P^T B-fragment: dest (g,c,r) needs P[q=c][key = kb + 8g + r];
    // source lane (G,c) holds p[reg] (keys kb+4G+reg) and p[4+reg] (keys kb+16+4G+reg)
    short8 pf;
#pragma unroll
    for (int r = 0; r < 8; r++) {
      const int G = (2 * g + (r >> 2)) & 3;
      const int src = c + (G << 4);
      const float pa = __shfl(p[r & 3], src, 64);
      const float pb = __shfl(p[4 + (r & 3)], src, 64);
      pf[r] = (short)f2bf(g >= 2 ? pb : pa);
    }

    // V^T A-fragments + PV MFMA: masked keys have p=0 so garbage rows are harmless
#pragma unroll
    for (int dc = 0; dc < 4; dc++) {
      const ushort_t* vp = V + (size_t)(kb + g * 8) * C3 + dc * 16 + c;
      short8 vf;
#pragma unroll
      for (int r = 0; r < 8; r++) vf[r] = (short)vp[(size_t)r * C3];
      yacc[dc] = __builtin_amdgcn_mfma_f32_16x16x32_bf16(vf, pf, yacc[dc], 0, 0, 0);
    }
  }

  const float inv = 1.0f / ssum;
  const int qg = qbase + c;
  ushort_t* yp = y + (size_t)(b * T + qg) * Cc + h * 64;
#pragma unroll
  for (int dc = 0; dc < 4; dc++)
#pragma unroll
    for (int r = 0; r < 4; r++)
      yp[dc * 16 + g * 4 + r] = f2bf(yacc[dc][r] * inv);
}

// ---------------------------------------------------------------------------
extern "C" void kernel_launch(void* const* d_in, const int* in_sizes, int n_in,
                              void* d_out, int out_size, void* d_ws, size_t ws_size,
                              hipStream_t stream) {
  const float* x = (const float*)d_in[0];     // (4, 2048, 1024)
  const float* Wat = (const float*)d_in[1];   // (1024, 3072)
  const float* Wpr = (const float*)d_in[2];   // (1024, 1024)
  float* out = (float*)d_out;                 // (4, 2048, 1024)

  const int T = 2048, B = 4, H = 16, Cc = 1024;
  const int M = B * T;  // 8192

  char* ws = (char*)d_ws;
  const size_t MB = 1024 * 1024;
  ushort_t* xb = (ushort_t*)ws;                 // 16 MB
  ushort_t* wat = (ushort_t*)(ws + 16 * MB);    // 6 MB
  ushort_t* wpt = (ushort_t*)(ws + 24 * MB);    // 2 MB
  ushort_t* qkv = (ushort_t*)(ws + 32 * MB);    // 48 MB
  ushort_t* yb = (ushort_t*)(ws + 80 * MB);     // 16 MB

  // 1. convert inputs to bf16 (weights transposed to [N][K] for the GEMM B-path)
  k_f32_to_bf16<<<dim3((M * Cc) / (8 * 256)), 256, 0, stream>>>(x, xb);
  k_transpose_bf16<<<dim3(3072 / 32, 1024 / 32), 256, 0, stream>>>(Wat, wat, 1024, 3072);
  k_transpose_bf16<<<dim3(1024 / 32, 1024 / 32), 256, 0, stream>>>(Wpr, wpt, 1024, 1024);

  // 2. qkv = x @ W_attn   (8192 x 3072)
  k_gemm_bt<true><<<dim3(3072 / 128, M / 128), 256, 0, stream>>>(xb, wat, qkv, 3072, 1024);

  // 3. causal flash attention -> y (8192 x 1024 bf16)
  k_attn<<<dim3(T / 64, H, B), 256, 0, stream>>>(qkv, yb);

  // 4. out = y @ W_proj   (8192 x 1024, fp32)
  k_gemm_bt<false><<<dim3(1024 / 128, M / 128), 256, 0, stream>>>(yb, wpt, out, 1024, 1024);
}